// Round 17
// baseline (338.181 us; speedup 1.0000x reference)
//
#include <hip/hip_runtime.h>
#include <hip/hip_bf16.h>
#include <math.h>

// Problem constants (B=2,S=1024 -> T=2048; D=1024; H=4096; E=8; top-2)
#define NTOK 2048
#define DDIM 1024
#define HDIM 4096
#define NEXP 8
#define NROWS (3 * NTOK)
#define KSPLIT2 2

typedef __bf16 bf16x8 __attribute__((ext_vector_type(8)));
typedef float f32x4 __attribute__((ext_vector_type(4)));
typedef __attribute__((address_space(1))) char as1_char;
typedef __attribute__((address_space(3))) char as3_char;

__device__ __forceinline__ void async16(const void* g, void* l) {
  __builtin_amdgcn_global_load_lds((as1_char*)g, (as3_char*)l, 16, 0, 0);
}

// Branch-free erf (A-S 7.1.26) -> exact-form gelu.
__device__ __forceinline__ float gelu_fast(float v) {
  const float x = v * 0.70710678118654752f;
  const float ax = fabsf(x);
  const float t = __builtin_amdgcn_rcpf(1.0f + 0.3275911f * ax);
  float p = 1.061405429f;
  p = p * t - 1.453152027f;
  p = p * t + 1.421413741f;
  p = p * t - 0.284496736f;
  p = p * t + 0.254829592f;
  const float y = 1.0f - p * t * __expf(-ax * ax);
  const float erfv = copysignf(y, x);
  return 0.5f * v * (1.0f + erfv);
}

// offsets recomputed from counts in-kernel: off(e) = sum counts[0..e);
// e==NEXP (shared) starts at 2*NTOK.
__device__ __forceinline__ int off_of(const int* __restrict__ counts, int e) {
  if (e >= NEXP) return 2 * NTOK;
  int s = 0;
  for (int i = 0; i < e; ++i) s += counts[i];
  return s;
}

// ---------------------------------------------------------------------------
// "pre" mega-launch (r10): gate (512 blocks x 4 tokens) + f32->bf16 cvt
// of x / W1 / Ws1 + out zeroing in ONE kernel.
// Blocks: gate 512 | x 1024 | W1 16384 | Ws1 2048 | zero_out 1024 = 20992.
// counts[] zeroed via hipMemsetAsync before this launch (gate atomics).
// ---------------------------------------------------------------------------
__device__ __forceinline__ void cvt2048(const float* __restrict__ src,
                                        __hip_bfloat16* __restrict__ dst,
                                        int tid) {
  const size_t i = (size_t)tid * 8;
  const float4 a = *(const float4*)(src + i);
  const float4 b = *(const float4*)(src + i + 4);
  union { __hip_bfloat16 h[8]; uint4 u; } p;
  p.h[0] = __float2bfloat16(a.x); p.h[1] = __float2bfloat16(a.y);
  p.h[2] = __float2bfloat16(a.z); p.h[3] = __float2bfloat16(a.w);
  p.h[4] = __float2bfloat16(b.x); p.h[5] = __float2bfloat16(b.y);
  p.h[6] = __float2bfloat16(b.z); p.h[7] = __float2bfloat16(b.w);
  *(uint4*)(dst + i) = p.u;
}

__global__ void __launch_bounds__(256) moe_pre(
    const float* __restrict__ x, const float* __restrict__ Wg,
    const float* __restrict__ bg, const float* __restrict__ bias,
    const float* __restrict__ W1, const float* __restrict__ Ws1,
    __hip_bfloat16* __restrict__ xbf, __hip_bfloat16* __restrict__ W1bf,
    __hip_bfloat16* __restrict__ Ws1bf, float* __restrict__ out,
    int* __restrict__ counts, int* __restrict__ topk_idx,
    float* __restrict__ topk_w, int* __restrict__ slot) {
  const int b = blockIdx.x, tid = threadIdx.x;
  if (b < 512) {
    // ---- gating: wave (tid>>6) of this block handles token b*4 + wave ----
    const int t = b * 4 + (tid >> 6);
    const int lane = tid & 63;
    float xv[16];
#pragma unroll
    for (int q = 0; q < 16; ++q) xv[q] = x[(size_t)t * DDIM + q * 64 + lane];
    float sc[NEXP];
#pragma unroll
    for (int e = 0; e < NEXP; ++e) {
      float s = 0.f;
#pragma unroll
      for (int q = 0; q < 16; ++q) s += xv[q] * Wg[(size_t)e * DDIM + q * 64 + lane];
#pragma unroll
      for (int o = 32; o > 0; o >>= 1) s += __shfl_xor(s, o, 64);
      sc[e] = 1.0f / (1.0f + expf(-(s + bg[e] + bias[e])));
    }
    if (lane == 0) {
      int k0 = 0;
      for (int e = 1; e < NEXP; ++e)
        if (sc[e] > sc[k0]) k0 = e;
      int k1 = (k0 == 0) ? 1 : 0;
      for (int e = 0; e < NEXP; ++e) {
        if (e == k0) continue;
        if (sc[e] > sc[k1]) k1 = e;
      }
      topk_idx[t * 2 + 0] = k0;
      topk_idx[t * 2 + 1] = k1;
      topk_w[t * 2 + 0] = sc[k0];
      topk_w[t * 2 + 1] = sc[k1];
      slot[t * 2 + 0] = atomicAdd(&counts[k0], 1);
      slot[t * 2 + 1] = atomicAdd(&counts[k1], 1);
    }
    return;
  }
  const int cb = b - 512;
  if (cb < 1024) { cvt2048(x + (size_t)cb * 2048, xbf + (size_t)cb * 2048, tid); return; }
  if (cb < 17408) { const size_t o = (size_t)(cb - 1024) * 2048; cvt2048(W1 + o, W1bf + o, tid); return; }
  if (cb < 19456) { const size_t o = (size_t)(cb - 17408) * 2048; cvt2048(Ws1 + o, Ws1bf + o, tid); return; }
  // zero out[]: 2048 f32 per block
  const size_t o = (size_t)(cb - 19456) * 2048 + (size_t)tid * 8;
  *(float4*)(out + o) = make_float4(0.f, 0.f, 0.f, 0.f);
  *(float4*)(out + o + 4) = make_float4(0.f, 0.f, 0.f, 0.f);
}

// ---------------------------------------------------------------------------
// Round-17 gemm1 core: m248v2-convergent geometry — 256x256 block tile,
// BK=64, 8 waves (2M x 4N), PER-WAVE 128x64 output (8x4 frags x 2 k-slices
// = 64 MFMA/wave/K-tile; acc 128 VGPR). The r16 counted-vmcnt 2-buffer
// schedule and the HW-verified 128B-row swizzle are carried over verbatim.
// LDS: A 256x128B = 32KB + B 32KB = 64KB/buf; x2 = 128KB -> 1 block/CU,
// 8 waves. Rationale: the m248v2 reference (grouped GEMM, our K, refcheck'd)
// hits 666 TF with this per-wave shape vs our measured ~440 TF at 64x32 —
// per-iter fixed costs (2 barriers + stage + vmcnt) amortize over 4x MFMA.
// r4's failure with this shape was grid starvation (384 blocks, 4 waves),
// not the shape itself. A-frags are processed in two 4-frag halves to bound
// live registers (bv 64 + av 32 + acc 128 ~ 224 < 256).
// Staging: wave w covers A rows [32w,+32) and B rows [32w,+32) as 4+4 DMAs
// -> counted vmcnt(8). Schedule correctness unchanged from r12/r16.
// ---------------------------------------------------------------------------
__device__ __forceinline__ void gemm1_core(const char* const ga[4], const char* const gb[4],
                                           char* sm, int Kbytes, int tid,
                                           f32x4 acc[8][4]) {
  const int w = tid >> 6, l = tid & 63;
  const int lr = l & 15, quad = l >> 4;
  const int wm = w >> 2, wn = w & 3;
  const int s8 = lr & 7;
  const int slot0 = (quad ^ s8) * 16;
  const int slot1 = ((4 + quad) ^ s8) * 16;
  const int abase = (wm * 128 + lr) * 128;         // A frag i2: +i2*2048
  const int bbase = 32768 + (wn * 64 + lr) * 128;  // B frag j: +j*2048
  const int niter = Kbytes >> 7;

  auto stage = [&](int it, int buf) {
    char* base = sm + buf * 65536;
    const int kb = it * 128;
#pragma unroll
    for (int q = 0; q < 4; ++q) {
      async16(ga[q] + kb, base + w * 4096 + q * 1024);
      async16(gb[q] + kb, base + 32768 + w * 4096 + q * 1024);
    }
  };

  stage(0, 0);
  for (int i = 0; i < niter; ++i) {
    const int cur = i & 1;
    if (i + 1 < niter) {
      stage(i + 1, cur ^ 1);                  // 8 own DMAs now outstanding
      __builtin_amdgcn_s_waitcnt(0x0F78);     // vmcnt(8): wait stage(i) only
    } else {
      __builtin_amdgcn_s_waitcnt(0x0F70);     // vmcnt(0): last tile
    }
    __builtin_amdgcn_s_barrier();             // raw: prefetch stays in flight
    const char* rb = sm + cur * 65536;
    bf16x8 bv[4][2];
#pragma unroll
    for (int j = 0; j < 4; ++j) {
      bv[j][0] = *(const bf16x8*)(rb + bbase + j * 2048 + slot0);
      bv[j][1] = *(const bf16x8*)(rb + bbase + j * 2048 + slot1);
    }
#pragma unroll
    for (int hb = 0; hb < 2; ++hb) {
      bf16x8 av[4][2];
#pragma unroll
      for (int i2 = 0; i2 < 4; ++i2) {
        av[i2][0] = *(const bf16x8*)(rb + abase + (hb * 4 + i2) * 2048 + slot0);
        av[i2][1] = *(const bf16x8*)(rb + abase + (hb * 4 + i2) * 2048 + slot1);
      }
#pragma unroll
      for (int s = 0; s < 2; ++s)
#pragma unroll
        for (int i2 = 0; i2 < 4; ++i2)
#pragma unroll
          for (int j = 0; j < 4; ++j)
            acc[hb * 4 + i2][j] = __builtin_amdgcn_mfma_f32_16x16x32_bf16(
                av[i2][s], bv[j][s], acc[hb * 4 + i2][j], 0, 0, 0);
    }
    __builtin_amdgcn_s_barrier();             // all reads of buf[cur] done
  }
}

// ---------------------------------------------------------------------------
// gemm2 core (r16 winner, unchanged): 128x64 / BK=64 / 48KB / 3 blocks/CU,
// 8 waves (4M x 2N), per-wave 32x32. Counted vmcnt(3).
// ---------------------------------------------------------------------------
__device__ __forceinline__ void gemm2_core(const char* const ga[2], const char* gb0,
                                           char* sm, int Kbytes, int tid,
                                           f32x4 acc[2][2]) {
  const int w = tid >> 6, l = tid & 63;
  const int lr = l & 15, quad = l >> 4;
  const int wm = w >> 1, wn = w & 1;
  const int s8 = lr & 7;
  const int slot0 = (quad ^ s8) * 16;
  const int slot1 = ((4 + quad) ^ s8) * 16;
  const int abase = (wm * 32 + lr) * 128;          // A frag i2: +i2*2048
  const int bbase = 16384 + (wn * 32 + lr) * 128;  // B frag j: +j*2048
  const int niter = Kbytes >> 7;

  auto stage = [&](int it, int buf) {
    char* base = sm + buf * 24576;
    const int kb = it * 128;
    async16(ga[0] + kb, base + w * 2048);
    async16(ga[1] + kb, base + w * 2048 + 1024);
    async16(gb0 + kb, base + 16384 + w * 1024);
  };

  stage(0, 0);
  for (int i = 0; i < niter; ++i) {
    const int cur = i & 1;
    if (i + 1 < niter) {
      stage(i + 1, cur ^ 1);                  // 3 own DMAs now outstanding
      __builtin_amdgcn_s_waitcnt(0x0F73);     // vmcnt(3): wait stage(i) only
    } else {
      __builtin_amdgcn_s_waitcnt(0x0F70);     // vmcnt(0): last tile
    }
    __builtin_amdgcn_s_barrier();             // raw: prefetch stays in flight
    const char* rb = sm + cur * 24576;
    bf16x8 av[2][2], bv[2][2];
#pragma unroll
    for (int i2 = 0; i2 < 2; ++i2) {
      av[i2][0] = *(const bf16x8*)(rb + abase + i2 * 2048 + slot0);
      av[i2][1] = *(const bf16x8*)(rb + abase + i2 * 2048 + slot1);
    }
#pragma unroll
    for (int j = 0; j < 2; ++j) {
      bv[j][0] = *(const bf16x8*)(rb + bbase + j * 2048 + slot0);
      bv[j][1] = *(const bf16x8*)(rb + bbase + j * 2048 + slot1);
    }
#pragma unroll
    for (int s = 0; s < 2; ++s)
#pragma unroll
      for (int i2 = 0; i2 < 2; ++i2)
#pragma unroll
        for (int j = 0; j < 2; ++j)
          acc[i2][j] = __builtin_amdgcn_mfma_f32_16x16x32_bf16(av[i2][s], bv[j][s], acc[i2][j], 0, 0, 0);
    __builtin_amdgcn_s_barrier();             // all reads of buf[cur] done
  }
}

// XCD group-swizzle: hw = (g%8) + 8*member + 64*(g/8). The 8 members of a
// group share hw%8 (same XCD under round-robin) and are dispatched within 64
// ids of each other. Proven on HW: gemm2 FETCH 300 -> ~120-240 MB (r7/r10).
__device__ __forceinline__ void xcd_decode(int hw, int& g, int& m) {
  m = (hw >> 3) & 7;
  g = (hw & 7) + 8 * (hw >> 6);
}

__global__ void moe_scatter(const int* __restrict__ counts,
                            const int* __restrict__ topk_idx, const float* __restrict__ topk_w,
                            const int* __restrict__ slot,
                            int* __restrict__ row_token, float* __restrict__ row_w) {
  const int t = blockIdx.x * blockDim.x + threadIdx.x;
  if (t >= NTOK) return;
#pragma unroll
  for (int k = 0; k < 2; ++k) {
    const int e = topk_idx[t * 2 + k];
    const int rg = off_of(counts, e) + slot[t * 2 + k];
    row_token[rg] = t;
    row_w[rg] = topk_w[t * 2 + k];
  }
  row_token[2 * NTOK + t] = t;
  row_w[2 * NTOK + t] = 1.0f;
}

// Distributed W2/Ws2 f32->bf16 conversion in gemm1 (1152-block grid, 512
// threads): 32768 elems/block = 16 iters x 2048.
// (1024 blocks -> W2's 33.55M, 128 -> Ws2's 4.19M; exact.)
__device__ __forceinline__ void cvt_w2_quota(int b, const float* __restrict__ W2,
                                             const float* __restrict__ Ws2,
                                             __hip_bfloat16* __restrict__ W2bf,
                                             __hip_bfloat16* __restrict__ Ws2bf,
                                             int tid) {
  const float* src;
  __hip_bfloat16* dst;
  size_t base;
  if (b < 1024) { src = W2; dst = W2bf; base = (size_t)b * 32768; }
  else          { src = Ws2; dst = Ws2bf; base = (size_t)(b - 1024) * 32768; }
#pragma unroll
  for (int k = 0; k < 16; ++k) {
    const size_t i = base + (size_t)k * 2048 + (size_t)tid * 4;
    const float4 a = *(const float4*)(src + i);
    union { __hip_bfloat16 h[4]; uint2 u; } p;
    p.h[0] = __float2bfloat16(a.x); p.h[1] = __float2bfloat16(a.y);
    p.h[2] = __float2bfloat16(a.z); p.h[3] = __float2bfloat16(a.w);
    *(uint2*)(dst + i) = p.u;
  }
}

// ---------------------------------------------------------------------------
// Grouped GEMM1: h1 = gelu(xbf @ W1bf^T + b1). 256x256 tiles, 512 threads
// (8 waves, per-wave 128x64), 1-D grid 1152 (16nt x 8mt x 9e), XCD-grouped:
// member m = nt&7; g = (nt>>3) + 2*mt + 16*e. + distributed W2 cvt epilogue.
// ---------------------------------------------------------------------------
__global__ void __launch_bounds__(512, 2) moe_gemm1(
    const __hip_bfloat16* __restrict__ xbf, const __hip_bfloat16* __restrict__ W1bf,
    const float* __restrict__ b1, const __hip_bfloat16* __restrict__ Ws1bf,
    const float* __restrict__ bs1, const int* __restrict__ counts,
    const int* __restrict__ row_token,
    __hip_bfloat16* __restrict__ h1, const float* __restrict__ W2,
    const float* __restrict__ Ws2, __hip_bfloat16* __restrict__ W2bf,
    __hip_bfloat16* __restrict__ Ws2bf) {
  __shared__ alignas(16) char sm[131072];
  const int tid = threadIdx.x;
  int g, m;
  xcd_decode(blockIdx.x, g, m);
  const int nt = m + 8 * (g & 1);   // 0..15 (H/256)
  const int mt = (g >> 1) & 7;      // 0..7  (NTOK/256)
  const int e = g >> 4;             // 0..8
  const int cnt = (e < NEXP) ? counts[e] : NTOK;
  if (mt * 256 >= cnt) {
    cvt_w2_quota(blockIdx.x, W2, Ws2, W2bf, Ws2bf, tid);
    return;
  }
  const int off = off_of(counts, e);
  const __hip_bfloat16* Bw = (e < NEXP) ? (W1bf + (size_t)e * HDIM * DDIM) : Ws1bf;
  const float* bb = (e < NEXP) ? (b1 + e * HDIM) : bs1;

  const int w = tid >> 6, l = tid & 63;
  const int rl8 = l >> 3;                    // 0..7 row within an 8-row DMA
  const int cg = ((l & 7) ^ rl8) * 16;       // pre-swizzled global 16B chunk

  // wave w stages A rows [32w,+32) (4 DMAs) and B rows [32w,+32) (4 DMAs)
  const char* ga[4];
  const char* gb[4];
#pragma unroll
  for (int q = 0; q < 4; ++q) {
    const int r = mt * 256 + w * 32 + q * 8 + rl8;
    const int c = (r < cnt) ? r : (cnt - 1);
    const int tok = row_token[off + c];
    ga[q] = (const char*)xbf + (size_t)tok * (DDIM * 2) + cg;
    gb[q] = (const char*)Bw + (size_t)(nt * 256 + w * 32 + q * 8 + rl8) * (DDIM * 2) + cg;
  }

  f32x4 acc[8][4] = {};
  gemm1_core(ga, gb, sm, DDIM * 2, tid, acc);

  const int lr = l & 15, quad = l >> 4, wm = w >> 2, wn = w & 3;
#pragma unroll
  for (int i = 0; i < 8; ++i) {
#pragma unroll
    for (int r = 0; r < 4; ++r) {
      const int rowe = mt * 256 + wm * 128 + i * 16 + quad * 4 + r;
      if (rowe >= cnt) continue;  // don't stomp next expert's rows
      const size_t orow = (size_t)(off + rowe) * HDIM;
#pragma unroll
      for (int j = 0; j < 4; ++j) {
        const int h = nt * 256 + wn * 64 + j * 16 + lr;
        const float v = acc[i][j][r] + bb[h];
        h1[orow + h] = __float2bfloat16(gelu_fast(v));
      }
    }
  }
  cvt_w2_quota(blockIdx.x, W2, Ws2, W2bf, Ws2bf, tid);
}

// ---------------------------------------------------------------------------
// Grouped GEMM2 (r16 winner, unchanged), split-K=2, 128x64 tiles, 512 thr:
// out[token,:] += w(row)*(h1[row,:] @ W2bf[e]^T) (+ w*b2[e] from K-chunk 0).
// 1-D grid 4608 (16nt x 2kc x 16mt x 9e), XCD-grouped; 3 blocks/CU.
// ---------------------------------------------------------------------------
__global__ void __launch_bounds__(512, 6) moe_gemm2(
    const __hip_bfloat16* __restrict__ h1, const __hip_bfloat16* __restrict__ W2bf,
    const float* __restrict__ b2, const __hip_bfloat16* __restrict__ Ws2bf,
    const float* __restrict__ bs2, const int* __restrict__ counts,
    const int* __restrict__ row_token,
    const float* __restrict__ row_w, float* __restrict__ out) {
  __shared__ alignas(16) char sm[49152];
  int g, m;
  xcd_decode(blockIdx.x, g, m);
  const int nt = m + 8 * (g & 1);  // 0..15 (D/64)
  const int kc = (g >> 1) & 1;     // K-chunk
  const int mt = (g >> 2) & 15;
  const int e = g >> 6;
  const int cnt = (e < NEXP) ? counts[e] : NTOK;
  if (mt * 128 >= cnt) return;
  const int off = off_of(counts, e);
  const __hip_bfloat16* Bw = (e < NEXP) ? (W2bf + (size_t)e * DDIM * HDIM) : Ws2bf;
  const float* bb = (e < NEXP) ? (b2 + e * DDIM) : bs2;

  const int tid = threadIdx.x;
  const int w = tid >> 6, l = tid & 63;
  const int rl8 = l >> 3;
  const int cg = ((l & 7) ^ rl8) * 16;
  const int KB = (HDIM * 2) / KSPLIT2;   // 4096 bytes per chunk
  const size_t kofs = (size_t)kc * KB;

  // wave w stages A rows [16w,+16) (2 DMAs) and B rows [8w,+8) (1 DMA).
  // A rows contiguous in grouped h1; rows >= cnt read the next group's valid
  // (finite) data and are discarded at the store guard.
  const char* ga[2];
#pragma unroll
  for (int q = 0; q < 2; ++q) {
    const int ar = mt * 128 + (2 * w + q) * 8 + rl8;
    ga[q] = (const char*)h1 + (size_t)(off + ar) * (HDIM * 2) + kofs + cg;
  }
  const char* gb0 = (const char*)Bw +
      (size_t)(nt * 64 + w * 8 + rl8) * (HDIM * 2) + kofs + cg;

  f32x4 acc[2][2] = {};
  gemm2_core(ga, gb0, sm, KB, tid, acc);

  const int lr = l & 15, quad = l >> 4, wm = w >> 1, wn = w & 1;
#pragma unroll
  for (int i = 0; i < 2; ++i) {
#pragma unroll
    for (int r = 0; r < 4; ++r) {
      const int rowe = mt * 128 + wm * 32 + i * 16 + quad * 4 + r;
      if (rowe >= cnt) continue;
      const int rg = off + rowe;
      const int tok = row_token[rg];
      const float wt = row_w[rg];
#pragma unroll
      for (int j = 0; j < 2; ++j) {
        const int d = nt * 64 + wn * 32 + j * 16 + lr;
        const float base = (kc == 0) ? bb[d] : 0.f;  // bias once per output
        atomicAdd(&out[(size_t)tok * DDIM + d], wt * (acc[i][j][r] + base));
      }
    }
  }
}

// ---------------------------------------------------------------------------
extern "C" void kernel_launch(void* const* d_in, const int* in_sizes, int n_in,
                              void* d_out, int out_size, void* d_ws, size_t ws_size,
                              hipStream_t stream) {
  (void)in_sizes; (void)n_in; (void)out_size; (void)ws_size;
  const float* x    = (const float*)d_in[0];
  const float* Wg   = (const float*)d_in[1];
  const float* bg   = (const float*)d_in[2];
  const float* bias = (const float*)d_in[3];
  const float* W1   = (const float*)d_in[4];
  const float* b1   = (const float*)d_in[5];
  const float* W2   = (const float*)d_in[6];
  const float* b2   = (const float*)d_in[7];
  const float* Ws1  = (const float*)d_in[8];
  const float* bs1  = (const float*)d_in[9];
  const float* Ws2  = (const float*)d_in[10];
  const float* bs2  = (const float*)d_in[11];
  float* out = (float*)d_out;

  char* ws = (char*)d_ws;
  size_t cur = 0;
  auto take = [&](size_t b) -> void* {
    void* p = ws + cur;
    cur += (b + 255) & ~(size_t)255;
    return p;
  };
  int* counts    = (int*)take(NEXP * 4);
  int* topk_idx  = (int*)take(NTOK * 2 * 4);
  float* topk_w  = (float*)take(NTOK * 2 * 4);
  int* slot      = (int*)take(NTOK * 2 * 4);
  int* row_token = (int*)take(NROWS * 4);
  float* row_w   = (float*)take(NROWS * 4);
  __hip_bfloat16* xbf   = (__hip_bfloat16*)take((size_t)NTOK * DDIM * 2);        //  4 MB
  __hip_bfloat16* W1bf  = (__hip_bfloat16*)take((size_t)NEXP * HDIM * DDIM * 2); // 67 MB
  __hip_bfloat16* W2bf  = (__hip_bfloat16*)take((size_t)NEXP * DDIM * HDIM * 2); // 67 MB
  __hip_bfloat16* Ws1bf = (__hip_bfloat16*)take((size_t)HDIM * DDIM * 2);        //  8 MB
  __hip_bfloat16* Ws2bf = (__hip_bfloat16*)take((size_t)DDIM * HDIM * 2);        //  8 MB
  __hip_bfloat16* h1    = (__hip_bfloat16*)take((size_t)(NROWS + 64) * HDIM * 2);// 51 MB

  // counts must be zero before gate atomics (gate lives inside moe_pre).
  hipMemsetAsync(counts, 0, NEXP * sizeof(int), stream);

  // gate + cvt(x, W1, Ws1) + zero(out), one launch
  moe_pre<<<20992, 256, 0, stream>>>(x, Wg, bg, bias, W1, Ws1,
                                     xbf, W1bf, Ws1bf, out,
                                     counts, topk_idx, topk_w, slot);

  // scatter computes expert offsets from counts inline
  moe_scatter<<<NTOK / 256, 256, 0, stream>>>(counts, topk_idx, topk_w, slot,
                                              row_token, row_w);

  // gemm1 (256x256, BK=64, 8 waves, per-wave 128x64, XCD-grouped)
  // + distributed W2/Ws2 cvt
  moe_gemm1<<<1152, 512, 0, stream>>>(xbf, W1bf, b1, Ws1bf, bs1, counts,
                                      row_token, h1, W2, Ws2, W2bf, Ws2bf);

  // gemm2 (r16 winner): 128x64, BK=64, 8 waves, split-K=2, 3 blocks/CU
  moe_gemm2<<<4608, 512, 0, stream>>>(h1, W2bf, b2, Ws2bf, bs2, counts,
                                      row_token, row_w, out);
}

// Round 18
// 296.562 us; speedup vs baseline: 1.1403x; 1.1403x over previous
//
#include <hip/hip_runtime.h>
#include <hip/hip_bf16.h>
#include <math.h>

// Problem constants (B=2,S=1024 -> T=2048; D=1024; H=4096; E=8; top-2)
#define NTOK 2048
#define DDIM 1024
#define HDIM 4096
#define NEXP 8
#define NROWS (3 * NTOK)
#define KSPLIT2 2

typedef __bf16 bf16x8 __attribute__((ext_vector_type(8)));
typedef float f32x4 __attribute__((ext_vector_type(4)));
typedef __attribute__((address_space(1))) char as1_char;
typedef __attribute__((address_space(3))) char as3_char;

__device__ __forceinline__ void async16(const void* g, void* l) {
  __builtin_amdgcn_global_load_lds((as1_char*)g, (as3_char*)l, 16, 0, 0);
}

// Branch-free erf (A-S 7.1.26) -> exact-form gelu.
__device__ __forceinline__ float gelu_fast(float v) {
  const float x = v * 0.70710678118654752f;
  const float ax = fabsf(x);
  const float t = __builtin_amdgcn_rcpf(1.0f + 0.3275911f * ax);
  float p = 1.061405429f;
  p = p * t - 1.453152027f;
  p = p * t + 1.421413741f;
  p = p * t - 0.284496736f;
  p = p * t + 0.254829592f;
  const float y = 1.0f - p * t * __expf(-ax * ax);
  const float erfv = copysignf(y, x);
  return 0.5f * v * (1.0f + erfv);
}

// offsets recomputed from counts in-kernel: off(e) = sum counts[0..e);
// e==NEXP (shared) starts at 2*NTOK.
__device__ __forceinline__ int off_of(const int* __restrict__ counts, int e) {
  if (e >= NEXP) return 2 * NTOK;
  int s = 0;
  for (int i = 0; i < e; ++i) s += counts[i];
  return s;
}

// ---------------------------------------------------------------------------
// "pre" mega-launch (r10): gate (512 blocks x 4 tokens) + f32->bf16 cvt
// of x / W1 / Ws1 + out zeroing in ONE kernel.
// Blocks: gate 512 | x 1024 | W1 16384 | Ws1 2048 | zero_out 1024 = 20992.
// counts[] zeroed via hipMemsetAsync before this launch (gate atomics).
// ---------------------------------------------------------------------------
__device__ __forceinline__ void cvt2048(const float* __restrict__ src,
                                        __hip_bfloat16* __restrict__ dst,
                                        int tid) {
  const size_t i = (size_t)tid * 8;
  const float4 a = *(const float4*)(src + i);
  const float4 b = *(const float4*)(src + i + 4);
  union { __hip_bfloat16 h[8]; uint4 u; } p;
  p.h[0] = __float2bfloat16(a.x); p.h[1] = __float2bfloat16(a.y);
  p.h[2] = __float2bfloat16(a.z); p.h[3] = __float2bfloat16(a.w);
  p.h[4] = __float2bfloat16(b.x); p.h[5] = __float2bfloat16(b.y);
  p.h[6] = __float2bfloat16(b.z); p.h[7] = __float2bfloat16(b.w);
  *(uint4*)(dst + i) = p.u;
}

__global__ void __launch_bounds__(256) moe_pre(
    const float* __restrict__ x, const float* __restrict__ Wg,
    const float* __restrict__ bg, const float* __restrict__ bias,
    const float* __restrict__ W1, const float* __restrict__ Ws1,
    __hip_bfloat16* __restrict__ xbf, __hip_bfloat16* __restrict__ W1bf,
    __hip_bfloat16* __restrict__ Ws1bf, float* __restrict__ out,
    int* __restrict__ counts, int* __restrict__ topk_idx,
    float* __restrict__ topk_w, int* __restrict__ slot) {
  const int b = blockIdx.x, tid = threadIdx.x;
  if (b < 512) {
    // ---- gating: wave (tid>>6) of this block handles token b*4 + wave ----
    const int t = b * 4 + (tid >> 6);
    const int lane = tid & 63;
    float xv[16];
#pragma unroll
    for (int q = 0; q < 16; ++q) xv[q] = x[(size_t)t * DDIM + q * 64 + lane];
    float sc[NEXP];
#pragma unroll
    for (int e = 0; e < NEXP; ++e) {
      float s = 0.f;
#pragma unroll
      for (int q = 0; q < 16; ++q) s += xv[q] * Wg[(size_t)e * DDIM + q * 64 + lane];
#pragma unroll
      for (int o = 32; o > 0; o >>= 1) s += __shfl_xor(s, o, 64);
      sc[e] = 1.0f / (1.0f + expf(-(s + bg[e] + bias[e])));
    }
    if (lane == 0) {
      int k0 = 0;
      for (int e = 1; e < NEXP; ++e)
        if (sc[e] > sc[k0]) k0 = e;
      int k1 = (k0 == 0) ? 1 : 0;
      for (int e = 0; e < NEXP; ++e) {
        if (e == k0) continue;
        if (sc[e] > sc[k1]) k1 = e;
      }
      topk_idx[t * 2 + 0] = k0;
      topk_idx[t * 2 + 1] = k1;
      topk_w[t * 2 + 0] = sc[k0];
      topk_w[t * 2 + 1] = sc[k1];
      slot[t * 2 + 0] = atomicAdd(&counts[k0], 1);
      slot[t * 2 + 1] = atomicAdd(&counts[k1], 1);
    }
    return;
  }
  const int cb = b - 512;
  if (cb < 1024) { cvt2048(x + (size_t)cb * 2048, xbf + (size_t)cb * 2048, tid); return; }
  if (cb < 17408) { const size_t o = (size_t)(cb - 1024) * 2048; cvt2048(W1 + o, W1bf + o, tid); return; }
  if (cb < 19456) { const size_t o = (size_t)(cb - 17408) * 2048; cvt2048(Ws1 + o, Ws1bf + o, tid); return; }
  // zero out[]: 2048 f32 per block
  const size_t o = (size_t)(cb - 19456) * 2048 + (size_t)tid * 8;
  *(float4*)(out + o) = make_float4(0.f, 0.f, 0.f, 0.f);
  *(float4*)(out + o + 4) = make_float4(0.f, 0.f, 0.f, 0.f);
}

// ---------------------------------------------------------------------------
// gemm1 core (r16 measured optimum): 128x128 / BK=64 (128B LDS rows = full
// cache lines) / 2-buffer / counted-vmcnt engine with 8 WAVES (512 thr,
// 2M x 4N wave grid, per-wave 64x32 = 4x2 frags x 2 k-slices).
// LDS 64KB -> 2 blocks/CU, 16 waves/CU; active 1536 blocks = 3.0 rounds.
// r17 lesson (3rd confirmation): >=256-wide tiles -> 1 block/CU starves
// this problem's ragged grouped grids; residency + round quantization
// dominate per-wave MFMA amortization here.
// Staging: wave w covers A rows [16w,+16) and B rows [16w,+16) as 2+2 DMAs
// -> counted vmcnt(4) (stage(i+1) stays in flight across the barrier).
// Swizzle (HW-verified conflict-free): store logical chunk c of row r at
// slot c^(r&7) via pre-swizzled GLOBAL chunk (lane l fetches chunk
// (l&7)^(l>>3) of row l>>3; LDS dest linear); read slot (4s+quad)^(lr&7).
// Schedule correctness: stage(i+1) overwrites buf cur^1 whose readers passed
// the trailing barrier of iter i-1; per-wave vmcnt before the leading
// barrier guarantees own stage(i) DMAs landed; the barrier publishes them.
// ---------------------------------------------------------------------------
__device__ __forceinline__ void gemm_core(const char* const ga[2], const char* const gb[2],
                                          char* sm, int Kbytes, int tid,
                                          f32x4 acc[4][2]) {
  const int w = tid >> 6, l = tid & 63;
  const int lr = l & 15, quad = l >> 4;
  const int wm = w >> 2, wn = w & 3;
  const int s8 = lr & 7;
  const int slot0 = (quad ^ s8) * 16;
  const int slot1 = ((4 + quad) ^ s8) * 16;
  const int abase = (wm * 64 + lr) * 128;          // A frag i2: +i2*2048
  const int bbase = 16384 + (wn * 32 + lr) * 128;  // B frag j: +j*2048
  const int niter = Kbytes >> 7;

  auto stage = [&](int it, int buf) {
    char* base = sm + buf * 32768;
    const int kb = it * 128;
#pragma unroll
    for (int q = 0; q < 2; ++q) {
      async16(ga[q] + kb, base + w * 2048 + q * 1024);
      async16(gb[q] + kb, base + 16384 + w * 2048 + q * 1024);
    }
  };

  stage(0, 0);
  for (int i = 0; i < niter; ++i) {
    const int cur = i & 1;
    if (i + 1 < niter) {
      stage(i + 1, cur ^ 1);                  // 4 own DMAs now outstanding
      __builtin_amdgcn_s_waitcnt(0x0F74);     // vmcnt(4): wait stage(i) only
    } else {
      __builtin_amdgcn_s_waitcnt(0x0F70);     // vmcnt(0): last tile
    }
    __builtin_amdgcn_s_barrier();             // raw: prefetch stays in flight
    const char* rb = sm + cur * 32768;
    bf16x8 av[4][2], bv[2][2];
#pragma unroll
    for (int i2 = 0; i2 < 4; ++i2) {
      av[i2][0] = *(const bf16x8*)(rb + abase + i2 * 2048 + slot0);
      av[i2][1] = *(const bf16x8*)(rb + abase + i2 * 2048 + slot1);
    }
#pragma unroll
    for (int j = 0; j < 2; ++j) {
      bv[j][0] = *(const bf16x8*)(rb + bbase + j * 2048 + slot0);
      bv[j][1] = *(const bf16x8*)(rb + bbase + j * 2048 + slot1);
    }
#pragma unroll
    for (int s = 0; s < 2; ++s)
#pragma unroll
      for (int i2 = 0; i2 < 4; ++i2)
#pragma unroll
        for (int j = 0; j < 2; ++j)
          acc[i2][j] = __builtin_amdgcn_mfma_f32_16x16x32_bf16(av[i2][s], bv[j][s], acc[i2][j], 0, 0, 0);
    __builtin_amdgcn_s_barrier();             // all reads of buf[cur] done
  }
}

// ---------------------------------------------------------------------------
// gemm2 core (r16 measured optimum): 128x64 / BK=64 / 48KB / 3 blocks/CU,
// 8 waves (4M x 2N), per-wave 32x32. Counted vmcnt(3). Waves/CU = 24.
// Active 1536 blocks at 3/CU = 2.0 exact rounds of 768 resident slots.
// ---------------------------------------------------------------------------
__device__ __forceinline__ void gemm2_core(const char* const ga[2], const char* gb0,
                                           char* sm, int Kbytes, int tid,
                                           f32x4 acc[2][2]) {
  const int w = tid >> 6, l = tid & 63;
  const int lr = l & 15, quad = l >> 4;
  const int wm = w >> 1, wn = w & 1;
  const int s8 = lr & 7;
  const int slot0 = (quad ^ s8) * 16;
  const int slot1 = ((4 + quad) ^ s8) * 16;
  const int abase = (wm * 32 + lr) * 128;          // A frag i2: +i2*2048
  const int bbase = 16384 + (wn * 32 + lr) * 128;  // B frag j: +j*2048
  const int niter = Kbytes >> 7;

  auto stage = [&](int it, int buf) {
    char* base = sm + buf * 24576;
    const int kb = it * 128;
    async16(ga[0] + kb, base + w * 2048);
    async16(ga[1] + kb, base + w * 2048 + 1024);
    async16(gb0 + kb, base + 16384 + w * 1024);
  };

  stage(0, 0);
  for (int i = 0; i < niter; ++i) {
    const int cur = i & 1;
    if (i + 1 < niter) {
      stage(i + 1, cur ^ 1);                  // 3 own DMAs now outstanding
      __builtin_amdgcn_s_waitcnt(0x0F73);     // vmcnt(3): wait stage(i) only
    } else {
      __builtin_amdgcn_s_waitcnt(0x0F70);     // vmcnt(0): last tile
    }
    __builtin_amdgcn_s_barrier();             // raw: prefetch stays in flight
    const char* rb = sm + cur * 24576;
    bf16x8 av[2][2], bv[2][2];
#pragma unroll
    for (int i2 = 0; i2 < 2; ++i2) {
      av[i2][0] = *(const bf16x8*)(rb + abase + i2 * 2048 + slot0);
      av[i2][1] = *(const bf16x8*)(rb + abase + i2 * 2048 + slot1);
    }
#pragma unroll
    for (int j = 0; j < 2; ++j) {
      bv[j][0] = *(const bf16x8*)(rb + bbase + j * 2048 + slot0);
      bv[j][1] = *(const bf16x8*)(rb + bbase + j * 2048 + slot1);
    }
#pragma unroll
    for (int s = 0; s < 2; ++s)
#pragma unroll
      for (int i2 = 0; i2 < 2; ++i2)
#pragma unroll
        for (int j = 0; j < 2; ++j)
          acc[i2][j] = __builtin_amdgcn_mfma_f32_16x16x32_bf16(av[i2][s], bv[j][s], acc[i2][j], 0, 0, 0);
    __builtin_amdgcn_s_barrier();             // all reads of buf[cur] done
  }
}

// XCD group-swizzle: hw = (g%8) + 8*member + 64*(g/8). The 8 members of a
// group share hw%8 (same XCD under round-robin) and are dispatched within 64
// ids of each other. Proven on HW: gemm2 FETCH 300 -> ~120-240 MB (r7/r10).
__device__ __forceinline__ void xcd_decode(int hw, int& g, int& m) {
  m = (hw >> 3) & 7;
  g = (hw & 7) + 8 * (hw >> 6);
}

__global__ void moe_scatter(const int* __restrict__ counts,
                            const int* __restrict__ topk_idx, const float* __restrict__ topk_w,
                            const int* __restrict__ slot,
                            int* __restrict__ row_token, float* __restrict__ row_w) {
  const int t = blockIdx.x * blockDim.x + threadIdx.x;
  if (t >= NTOK) return;
#pragma unroll
  for (int k = 0; k < 2; ++k) {
    const int e = topk_idx[t * 2 + k];
    const int rg = off_of(counts, e) + slot[t * 2 + k];
    row_token[rg] = t;
    row_w[rg] = topk_w[t * 2 + k];
  }
  row_token[2 * NTOK + t] = t;
  row_w[2 * NTOK + t] = 1.0f;
}

// Distributed W2/Ws2 f32->bf16 conversion in gemm1 (4608-block split, 512
// threads/block): 8192 elems/block = 4 iters x 2048
// (4096 blocks -> W2's 33.55M, 512 -> Ws2's 4.19M; exact).
__device__ __forceinline__ void cvt_w2_quota(int b, const float* __restrict__ W2,
                                             const float* __restrict__ Ws2,
                                             __hip_bfloat16* __restrict__ W2bf,
                                             __hip_bfloat16* __restrict__ Ws2bf,
                                             int tid) {
  const float* src;
  __hip_bfloat16* dst;
  size_t base;
  if (b < 4096) { src = W2; dst = W2bf; base = (size_t)b * 8192; }
  else          { src = Ws2; dst = Ws2bf; base = (size_t)(b - 4096) * 8192; }
#pragma unroll
  for (int k = 0; k < 4; ++k) {
    const size_t i = base + (size_t)k * 2048 + (size_t)tid * 4;
    const float4 a = *(const float4*)(src + i);
    union { __hip_bfloat16 h[4]; uint2 u; } p;
    p.h[0] = __float2bfloat16(a.x); p.h[1] = __float2bfloat16(a.y);
    p.h[2] = __float2bfloat16(a.z); p.h[3] = __float2bfloat16(a.w);
    *(uint2*)(dst + i) = p.u;
  }
}

// ---------------------------------------------------------------------------
// Grouped GEMM1: h1 = gelu(xbf @ W1bf^T + b1). 128x128 tiles, 512 threads
// (8 waves), 1-D grid 4608, XCD-grouped + distributed W2 cvt epilogue.
// ---------------------------------------------------------------------------
__global__ void __launch_bounds__(512, 4) moe_gemm1(
    const __hip_bfloat16* __restrict__ xbf, const __hip_bfloat16* __restrict__ W1bf,
    const float* __restrict__ b1, const __hip_bfloat16* __restrict__ Ws1bf,
    const float* __restrict__ bs1, const int* __restrict__ counts,
    const int* __restrict__ row_token,
    __hip_bfloat16* __restrict__ h1, const float* __restrict__ W2,
    const float* __restrict__ Ws2, __hip_bfloat16* __restrict__ W2bf,
    __hip_bfloat16* __restrict__ Ws2bf) {
  __shared__ alignas(16) char sm[65536];
  const int tid = threadIdx.x;
  int g, m;
  xcd_decode(blockIdx.x, g, m);
  const int nt = m + 8 * (g & 3);
  const int mt = (g >> 2) & 15;
  const int e = g >> 6;
  const int cnt = (e < NEXP) ? counts[e] : NTOK;
  if (mt * 128 >= cnt) {
    cvt_w2_quota(blockIdx.x, W2, Ws2, W2bf, Ws2bf, tid);
    return;
  }
  const int off = off_of(counts, e);
  const __hip_bfloat16* Bw = (e < NEXP) ? (W1bf + (size_t)e * HDIM * DDIM) : Ws1bf;
  const float* bb = (e < NEXP) ? (b1 + e * HDIM) : bs1;

  const int w = tid >> 6, l = tid & 63;
  const int rl8 = l >> 3;                    // 0..7 row within an 8-row DMA
  const int cg = ((l & 7) ^ rl8) * 16;       // pre-swizzled global 16B chunk

  // wave w stages A rows [16w,+16) (2 DMAs) and B rows [16w,+16) (2 DMAs)
  const char* ga[2];
  const char* gb[2];
#pragma unroll
  for (int q = 0; q < 2; ++q) {
    const int r = mt * 128 + (2 * w + q) * 8 + rl8;
    const int c = (r < cnt) ? r : (cnt - 1);
    const int tok = row_token[off + c];
    ga[q] = (const char*)xbf + (size_t)tok * (DDIM * 2) + cg;
    gb[q] = (const char*)Bw + (size_t)(nt * 128 + (2 * w + q) * 8 + rl8) * (DDIM * 2) + cg;
  }

  f32x4 acc[4][2] = {};
  gemm_core(ga, gb, sm, DDIM * 2, tid, acc);

  const int lr = l & 15, quad = l >> 4, wm = w >> 2, wn = w & 3;
#pragma unroll
  for (int i = 0; i < 4; ++i) {
#pragma unroll
    for (int r = 0; r < 4; ++r) {
      const int rowe = mt * 128 + wm * 64 + i * 16 + quad * 4 + r;
      if (rowe >= cnt) continue;  // don't stomp next expert's rows
      const size_t orow = (size_t)(off + rowe) * HDIM;
#pragma unroll
      for (int j = 0; j < 2; ++j) {
        const int h = nt * 128 + wn * 32 + j * 16 + lr;
        const float v = acc[i][j][r] + bb[h];
        h1[orow + h] = __float2bfloat16(gelu_fast(v));
      }
    }
  }
  cvt_w2_quota(blockIdx.x, W2, Ws2, W2bf, Ws2bf, tid);
}

// ---------------------------------------------------------------------------
// Grouped GEMM2, split-K=2, BM=128 x BN=64 tiles, 512 threads (8 waves):
// out[token,:] += w(row)*(h1[row,:] @ W2bf[e]^T) (+ w*b2[e] from K-chunk 0).
// 1-D grid 4608 (16nt x 2kc x 16mt x 9e), XCD-grouped; active 1536 blocks
// at 3/CU = 2.0 exact rounds of 768 resident slots.
// ---------------------------------------------------------------------------
__global__ void __launch_bounds__(512, 6) moe_gemm2(
    const __hip_bfloat16* __restrict__ h1, const __hip_bfloat16* __restrict__ W2bf,
    const float* __restrict__ b2, const __hip_bfloat16* __restrict__ Ws2bf,
    const float* __restrict__ bs2, const int* __restrict__ counts,
    const int* __restrict__ row_token,
    const float* __restrict__ row_w, float* __restrict__ out) {
  __shared__ alignas(16) char sm[49152];
  int g, m;
  xcd_decode(blockIdx.x, g, m);
  const int nt = m + 8 * (g & 1);  // 0..15 (D/64)
  const int kc = (g >> 1) & 1;     // K-chunk
  const int mt = (g >> 2) & 15;
  const int e = g >> 6;
  const int cnt = (e < NEXP) ? counts[e] : NTOK;
  if (mt * 128 >= cnt) return;
  const int off = off_of(counts, e);
  const __hip_bfloat16* Bw = (e < NEXP) ? (W2bf + (size_t)e * DDIM * HDIM) : Ws2bf;
  const float* bb = (e < NEXP) ? (b2 + e * DDIM) : bs2;

  const int tid = threadIdx.x;
  const int w = tid >> 6, l = tid & 63;
  const int rl8 = l >> 3;
  const int cg = ((l & 7) ^ rl8) * 16;
  const int KB = (HDIM * 2) / KSPLIT2;   // 4096 bytes per chunk
  const size_t kofs = (size_t)kc * KB;

  // wave w stages A rows [16w,+16) (2 DMAs) and B rows [8w,+8) (1 DMA).
  // A rows contiguous in grouped h1; rows >= cnt read the next group's valid
  // (finite) data and are discarded at the store guard.
  const char* ga[2];
#pragma unroll
  for (int q = 0; q < 2; ++q) {
    const int ar = mt * 128 + (2 * w + q) * 8 + rl8;
    ga[q] = (const char*)h1 + (size_t)(off + ar) * (HDIM * 2) + kofs + cg;
  }
  const char* gb0 = (const char*)Bw +
      (size_t)(nt * 64 + w * 8 + rl8) * (HDIM * 2) + kofs + cg;

  f32x4 acc[2][2] = {};
  gemm2_core(ga, gb0, sm, KB, tid, acc);

  const int lr = l & 15, quad = l >> 4, wm = w >> 1, wn = w & 1;
#pragma unroll
  for (int i = 0; i < 2; ++i) {
#pragma unroll
    for (int r = 0; r < 4; ++r) {
      const int rowe = mt * 128 + wm * 32 + i * 16 + quad * 4 + r;
      if (rowe >= cnt) continue;
      const int rg = off + rowe;
      const int tok = row_token[rg];
      const float wt = row_w[rg];
#pragma unroll
      for (int j = 0; j < 2; ++j) {
        const int d = nt * 64 + wn * 32 + j * 16 + lr;
        const float base = (kc == 0) ? bb[d] : 0.f;  // bias once per output
        atomicAdd(&out[(size_t)tok * DDIM + d], wt * (acc[i][j][r] + base));
      }
    }
  }
}

// ---------------------------------------------------------------------------
extern "C" void kernel_launch(void* const* d_in, const int* in_sizes, int n_in,
                              void* d_out, int out_size, void* d_ws, size_t ws_size,
                              hipStream_t stream) {
  (void)in_sizes; (void)n_in; (void)out_size; (void)ws_size;
  const float* x    = (const float*)d_in[0];
  const float* Wg   = (const float*)d_in[1];
  const float* bg   = (const float*)d_in[2];
  const float* bias = (const float*)d_in[3];
  const float* W1   = (const float*)d_in[4];
  const float* b1   = (const float*)d_in[5];
  const float* W2   = (const float*)d_in[6];
  const float* b2   = (const float*)d_in[7];
  const float* Ws1  = (const float*)d_in[8];
  const float* bs1  = (const float*)d_in[9];
  const float* Ws2  = (const float*)d_in[10];
  const float* bs2  = (const float*)d_in[11];
  float* out = (float*)d_out;

  char* ws = (char*)d_ws;
  size_t cur = 0;
  auto take = [&](size_t b) -> void* {
    void* p = ws + cur;
    cur += (b + 255) & ~(size_t)255;
    return p;
  };
  int* counts    = (int*)take(NEXP * 4);
  int* topk_idx  = (int*)take(NTOK * 2 * 4);
  float* topk_w  = (float*)take(NTOK * 2 * 4);
  int* slot      = (int*)take(NTOK * 2 * 4);
  int* row_token = (int*)take(NROWS * 4);
  float* row_w   = (float*)take(NROWS * 4);
  __hip_bfloat16* xbf   = (__hip_bfloat16*)take((size_t)NTOK * DDIM * 2);        //  4 MB
  __hip_bfloat16* W1bf  = (__hip_bfloat16*)take((size_t)NEXP * HDIM * DDIM * 2); // 67 MB
  __hip_bfloat16* W2bf  = (__hip_bfloat16*)take((size_t)NEXP * DDIM * HDIM * 2); // 67 MB
  __hip_bfloat16* Ws1bf = (__hip_bfloat16*)take((size_t)HDIM * DDIM * 2);        //  8 MB
  __hip_bfloat16* Ws2bf = (__hip_bfloat16*)take((size_t)DDIM * HDIM * 2);        //  8 MB
  __hip_bfloat16* h1    = (__hip_bfloat16*)take((size_t)(NROWS + 64) * HDIM * 2);// 51 MB

  // counts must be zero before gate atomics (gate lives inside moe_pre).
  hipMemsetAsync(counts, 0, NEXP * sizeof(int), stream);

  // gate + cvt(x, W1, Ws1) + zero(out), one launch
  moe_pre<<<20992, 256, 0, stream>>>(x, Wg, bg, bias, W1, Ws1,
                                     xbf, W1bf, Ws1bf, out,
                                     counts, topk_idx, topk_w, slot);

  // scatter computes expert offsets from counts inline
  moe_scatter<<<NTOK / 256, 256, 0, stream>>>(counts, topk_idx, topk_w, slot,
                                              row_token, row_w);

  // gemm1 (128x128, BK=64, 8 waves, XCD-grouped) + distributed W2/Ws2 cvt
  moe_gemm1<<<4608, 512, 0, stream>>>(xbf, W1bf, b1, Ws1bf, bs1, counts,
                                      row_token, h1, W2, Ws2, W2bf, Ws2bf);

  // gemm2 (128x64, BK=64, 8 waves, split-K=2, 3 blocks/CU)
  moe_gemm2<<<4608, 512, 0, stream>>>(h1, W2bf, b2, Ws2bf, bs2, counts,
                                      row_token, row_w, out);
}